// Round 11
// baseline (480.988 us; speedup 1.0000x reference)
//
#include <hip/hip_runtime.h>

#define NC 256
#define NB 32
#define HW4 1024
#define KC 768
#define BN_EPS 1e-5f
#define CG 64            // channels per apply block
#define TPB 267          // tickets per batch: 256 gap + 3 filt + 8 apply

typedef float f32x4 __attribute__((ext_vector_type(4)));

__device__ __forceinline__ int spin_until(const int* p, int target) {
    // agent-scope acquire spin with failsafe bound
    for (long it = 0; it < 400000000L; ++it) {
        if (__hip_atomic_load(p, __ATOMIC_ACQUIRE, __HIP_MEMORY_SCOPE_AGENT) >= target)
            return 1;
        __builtin_amdgcn_s_sleep(2);
    }
    return 0;
}

__global__ __launch_bounds__(256) void mega_kernel(
    const float* __restrict__ x, const float* __restrict__ cw,
    const float* __restrict__ bn_w, const float* __restrict__ bn_b,
    const float* __restrict__ bn_m, const float* __restrict__ bn_v,
    const float* __restrict__ gamma, const float* __restrict__ beta,
    float* __restrict__ out, int* __restrict__ ctrs,
    float* __restrict__ g, float* __restrict__ f) {
    const int t = threadIdx.x;
    __shared__ int s_ticket;
    if (t == 0) s_ticket = atomicAdd(&ctrs[0], 1);
    __syncthreads();
    const int tid   = s_ticket;
    const int batch = tid / TPB;
    const int r     = tid % TPB;
    int* gap_done  = ctrs + 16;    // [32]
    int* filt_done = ctrs + 64;    // [32]

    if (r < 256) {
        // ---------------- GAP: reduce plane (batch, c=r) ----------------
        const int c = r;
        const f32x4* xp = reinterpret_cast<const f32x4*>(x) + (size_t)(batch * NC + c) * HW4;
        float s = 0.f;
#pragma unroll
        for (int k = 0; k < 4; ++k) {
            f32x4 v = xp[t + k * 256];
            s += (v.x + v.y) + (v.z + v.w);
        }
#pragma unroll
        for (int off = 32; off > 0; off >>= 1) s += __shfl_down(s, off, 64);
        __shared__ float warp_sums[4];
        const int lane = t & 63, w = t >> 6;
        if (lane == 0) warp_sums[w] = s;
        __syncthreads();
        if (t == 0) {
            float tot = (warp_sums[0] + warp_sums[1]) + (warp_sums[2] + warp_sums[3]);
            g[batch * NC + c] = tot * (1.0f / 4096.0f);
            __threadfence();
            atomicAdd(&gap_done[batch], 1);
        }
    } else if (r < 259) {
        // ---------------- FILT: rows k*256..k*256+255 for this batch ----------------
        const int k = r - 256;
        __shared__ float gs[NC];
        __shared__ int ok_s;
        if (t == 0) ok_s = spin_until(&gap_done[batch], 256);
        __syncthreads();
        if (!ok_s) return;
        gs[t] = __hip_atomic_load(&g[batch * NC + t], __ATOMIC_RELAXED,
                                  __HIP_MEMORY_SCOPE_AGENT);
        __syncthreads();
        const int j = k * NC + t;                 // output row
        const float* wr = cw + (size_t)j * NC;
        float a0 = 0.f, a1 = 0.f, a2 = 0.f, a3 = 0.f;
#pragma unroll 4
        for (int c = 0; c < NC; c += 4) {
            a0 = fmaf(gs[c + 0], wr[c + 0], a0);
            a1 = fmaf(gs[c + 1], wr[c + 1], a1);
            a2 = fmaf(gs[c + 2], wr[c + 2], a2);
            a3 = fmaf(gs[c + 3], wr[c + 3], a3);
        }
        const float acc = (a0 + a1) + (a2 + a3);
        const float yn = (acc - bn_m[j]) * rsqrtf(bn_v[j] + BN_EPS) * bn_w[j] + bn_b[j];
        f[batch * KC + j] = tanhf(yn);
        __threadfence();
        __syncthreads();
        if (t == 0) atomicAdd(&filt_done[batch], 1);
    } else {
        // ---------------- APPLY: (batch, cgp, half), CG=64 channels ----------------
        const int aid  = r - 259;         // 0..7
        const int half = aid & 1;
        const int cgp  = aid >> 1;        // 0..3
        const int c0   = cgp * CG;
        __shared__ float f_s[3][CG];
        __shared__ float ga_s[CG], be_s[CG];
        __shared__ int ok_s;
        if (t == 0) ok_s = spin_until(&filt_done[batch], 3);
        __syncthreads();
        if (!ok_s) return;
        if (t < 192)
            f_s[t >> 6][t & 63] = __hip_atomic_load(
                &f[batch * KC + (t >> 6) * NC + c0 + (t & 63)],
                __ATOMIC_RELAXED, __HIP_MEMORY_SCOPE_AGENT);
        else
            ga_s[t - 192] = gamma[c0 + t - 192];
        if (t < CG) be_s[t] = beta[c0 + t];
        __syncthreads();

        const size_t bbase = (size_t)batch * NC * HW4;
        const f32x4* x4 = reinterpret_cast<const f32x4*>(x) + bbase;
        f32x4* o4 = reinterpret_cast<f32x4*>(out) + bbase;
        const int col0 = half * 512 + t;
        const int col1 = col0 + 256;

        f32x4 cur0 = x4[(size_t)c0 * HW4 + col0];
        f32x4 cur1 = x4[(size_t)c0 * HW4 + col1];
        f32x4 nxt0 = x4[(size_t)(c0 + 1) * HW4 + col0];
        f32x4 nxt1 = x4[(size_t)(c0 + 1) * HW4 + col1];
        f32x4 p20  = x4[(size_t)(c0 + 2) * HW4 + col0];
        f32x4 p21  = x4[(size_t)(c0 + 2) * HW4 + col1];
        f32x4 p30  = x4[(size_t)(c0 + 3) * HW4 + col0];
        f32x4 p31  = x4[(size_t)(c0 + 3) * HW4 + col1];
        f32x4 prv0, prv1;
        if (c0 == 0) { prv0 = nxt0; prv1 = nxt1; }
        else {
            prv0 = x4[(size_t)(c0 - 1) * HW4 + col0];
            prv1 = x4[(size_t)(c0 - 1) * HW4 + col1];
        }

#pragma unroll 4
        for (int ci = 0; ci < CG; ++ci) {
            const int c  = c0 + ci;
            const int cn = (c + 4 < NC) ? (c + 4) : (NC - 1);
            f32x4 nn0 = x4[(size_t)cn * HW4 + col0];
            f32x4 nn1 = x4[(size_t)cn * HW4 + col1];
            const float f0 = f_s[0][ci];
            const float f1 = f_s[1][ci];
            const float f2 = f_s[2][ci];
            const float ga = ga_s[ci];
            const float be = be_s[ci];
            const f32x4 xm0 = (c == 0) ? nxt0 : prv0;
            const f32x4 xm1 = (c == 0) ? nxt1 : prv1;
            const f32x4 xq0 = (c == NC - 1) ? prv0 : nxt0;
            const f32x4 xq1 = (c == NC - 1) ? prv1 : nxt1;
            f32x4 r0, r1;
            r0.x = fmaf(fmaf(f0, xm0.x, fmaf(f1, cur0.x, f2 * xq0.x)), ga, cur0.x * be);
            r0.y = fmaf(fmaf(f0, xm0.y, fmaf(f1, cur0.y, f2 * xq0.y)), ga, cur0.y * be);
            r0.z = fmaf(fmaf(f0, xm0.z, fmaf(f1, cur0.z, f2 * xq0.z)), ga, cur0.z * be);
            r0.w = fmaf(fmaf(f0, xm0.w, fmaf(f1, cur0.w, f2 * xq0.w)), ga, cur0.w * be);
            r1.x = fmaf(fmaf(f0, xm1.x, fmaf(f1, cur1.x, f2 * xq1.x)), ga, cur1.x * be);
            r1.y = fmaf(fmaf(f0, xm1.y, fmaf(f1, cur1.y, f2 * xq1.y)), ga, cur1.y * be);
            r1.z = fmaf(fmaf(f0, xm1.z, fmaf(f1, cur1.z, f2 * xq1.z)), ga, cur1.z * be);
            r1.w = fmaf(fmaf(f0, xm1.w, fmaf(f1, cur1.w, f2 * xq1.w)), ga, cur1.w * be);
            o4[(size_t)c * HW4 + col0] = r0;
            o4[(size_t)c * HW4 + col1] = r1;
            prv0 = cur0; cur0 = nxt0; nxt0 = p20; p20 = p30; p30 = nn0;
            prv1 = cur1; cur1 = nxt1; nxt1 = p21; p21 = p31; p31 = nn1;
        }
    }
}

extern "C" void kernel_launch(void* const* d_in, const int* in_sizes, int n_in,
                              void* d_out, int out_size, void* d_ws, size_t ws_size,
                              hipStream_t stream) {
    const float* x     = (const float*)d_in[0];
    const float* cw    = (const float*)d_in[1];
    const float* bn_w  = (const float*)d_in[2];
    const float* bn_b  = (const float*)d_in[3];
    const float* bn_m  = (const float*)d_in[4];
    const float* bn_v  = (const float*)d_in[5];
    const float* gamma = (const float*)d_in[6];
    const float* beta  = (const float*)d_in[7];
    float* out = (float*)d_out;

    int*   ctrs = (int*)d_ws;                                  // 4 KB counters
    float* g    = (float*)((char*)d_ws + 4096);                // 32 KB
    float* f    = (float*)((char*)d_ws + 4096 + 32768);        // 96 KB

    hipMemsetAsync(d_ws, 0, 4096, stream);                     // zero counters each call
    mega_kernel<<<NB * TPB, 256, 0, stream>>>(
        x, cw, bn_w, bn_b, bn_m, bn_v, gamma, beta, out, ctrs, g, f);
}